// Round 1
// baseline (1208.799 us; speedup 1.0000x reference)
//
#include <hip/hip_runtime.h>
#include <hip/hip_bf16.h>

#define HID 1000
#define CTX 2000
#define KP   2016          // K padded to 63*32
#define HP   1024          // H padded to 8*128
#define BATCH 64
#define NSEQ 1024
#define M_TOT (BATCH * NSEQ)   // 65536
#define WSTR 1024              // W_s row stride

typedef __attribute__((ext_vector_type(8))) short short8;
typedef __attribute__((ext_vector_type(4))) float floatx4;

// fp32 -> bf16 round-to-nearest-even (scalar, used in convertB)
__device__ __forceinline__ unsigned short f2bf(float x) {
    union { float f; unsigned u; } v; v.f = x;
    unsigned r = v.u + 0x7FFFu + ((v.u >> 16) & 1u);
    return (unsigned short)(r >> 16);
}

// packed fp32x2 -> bf16x2, single instruction (gfx950)
__device__ __forceinline__ unsigned pkbf(float lo, float hi) {
    unsigned r;
    asm("v_cvt_pk_bf16_f32 %0, %1, %2" : "=v"(r) : "v"(lo), "v"(hi));
    return r;
}

// async global->LDS, 16B per lane; LDS dest = wave-uniform base + lane*16
typedef const __attribute__((address_space(1))) unsigned glb_u32;
typedef __attribute__((address_space(3))) unsigned lds_u32;
__device__ __forceinline__ void gload16(const void* g, void* l) {
    __builtin_amdgcn_global_load_lds((glb_u32*)g, (lds_u32*)l, 16, 0, 0);
}

__global__ void zero_kernel(float* __restrict__ out, int n) {
    int i = blockIdx.x * 256 + threadIdx.x;
    if (i < n) out[i] = 0.0f;
}

// U_a (HID x CTX fp32) -> B_bf (HP x KP bf16), zero-pad rows >= HID, cols >= CTX
__global__ void convertB_kernel(const float* __restrict__ src, unsigned short* __restrict__ dst) {
    int row = blockIdx.x;          // 0..HP-1
    int t = threadIdx.x;
    if (t >= KP / 8) return;
    unsigned short pk[8];
    if (row < HID && t < CTX / 8) {
        const float* p = src + (size_t)row * CTX + t * 8;
        float4 a = *(const float4*)p;
        float4 b = *(const float4*)(p + 4);
        pk[0]=f2bf(a.x); pk[1]=f2bf(a.y); pk[2]=f2bf(a.z); pk[3]=f2bf(a.w);
        pk[4]=f2bf(b.x); pk[5]=f2bf(b.y); pk[6]=f2bf(b.z); pk[7]=f2bf(b.w);
    } else {
#pragma unroll
        for (int i = 0; i < 8; i++) pk[i] = 0;
    }
    *(short8*)(dst + (size_t)row * KP + t * 8) = *(short8*)pk;
}

// W_s[b,h] = sum_d s_prev[b,d] * W_a[h,d] — one wave per (b,h), coalesced row reads
__global__ void ws_kernel(const float* __restrict__ s_prev,
                          const float* __restrict__ W_a,
                          float* __restrict__ W_s) {
    int wave = threadIdx.x >> 6, lane = threadIdx.x & 63;
    int gw = blockIdx.x * 4 + wave;      // 0 .. 63999
    int b = gw / HID, h = gw % HID;
    const float* wr = W_a + (size_t)h * HID;
    const float* sr = s_prev + (size_t)b * HID;
    float acc = 0.0f;
#pragma unroll
    for (int it = 0; it < 4; ++it) {
        int idx = it * 64 + lane;        // float4 index, HID/4 = 250
        if (idx < HID / 4) {
            float4 w = *(const float4*)(wr + idx * 4);
            float4 s = *(const float4*)(sr + idx * 4);
            acc += w.x * s.x + w.y * s.y + w.z * s.z + w.w * s.w;
        }
    }
    acc += __shfl_xor(acc, 1);
    acc += __shfl_xor(acc, 2);
    acc += __shfl_xor(acc, 4);
    acc += __shfl_xor(acc, 8);
    acc += __shfl_xor(acc, 16);
    acc += __shfl_xor(acc, 32);
    if (lane == 0) W_s[b * WSTR + h] = acc;
}

// Fused GEMM: reads h_j fp32 directly (no convertA pass), converts to bf16
// in-register (v_cvt_pk_bf16_f32) and stages into double-buffered LDS.
// Grid = 512 m-panels x 8 h-tiles, XCD-chunked swizzle so the 8 h-blocks of
// one m-panel run lockstep on one XCD and share the A k-slice via L2.
// Single barrier per k-iter: stage(next) -> MFMA(cur) -> cvt/ds_write(next) -> sync.
__global__ __launch_bounds__(256, 3) void gemm_kernel(
        const float* __restrict__ A,           // h_j fp32, M_TOT x CTX
        const unsigned short* __restrict__ B,  // B_bf bf16, HP x KP
        const float* __restrict__ W_s, const float* __restrict__ v_a,
        float* __restrict__ out) {
    __shared__ __align__(16) unsigned short As[2 * 128 * 32];  // 2 x 8 KB
    __shared__ __align__(16) unsigned short Bs[2 * 128 * 32];  // 2 x 8 KB

    const int tid  = threadIdx.x;
    const int lane = tid & 63;
    const int wave = tid >> 6;
    const int wm = wave & 1, wh = wave >> 1;
    const int ln = lane & 15, quad = lane >> 4;

    // bijective XCD swizzle: xcd = bid&7 runs its 64 m-panels x 8 h in sequence
    const int bid = blockIdx.x;
    const int xcd = bid & 7, seq = bid >> 3;       // grid 4096 = 8*64*8
    const int m0 = (xcd * 64 + (seq >> 3)) * 128;  // m-panel base row
    const int ht = seq & 7;                        // h-tile of this block
    const int bb = m0 >> 10;                       // batch idx (tile never crosses b)

    // A reg-staging geometry: thread t -> row t>>1, 16-col half t&1
    const int arow = tid >> 1, ahalf = tid & 1;
    const float* abase = A + (size_t)(m0 + arow) * CTX + ahalf * 16;
    const int aoff = arow * 64 + ahalf * 32;       // byte offset in A LDS buffer

    // B staging via gload16: wave w, lane l -> row w*16 + (l>>2), col (l&3)*8
    const int srow = lane >> 2, scol = (lane & 3) * 8;
    const unsigned short* bbase0 = B + (size_t)(ht * 128 + wave * 16 + srow) * KP + scol;
    const unsigned short* bbase1 = bbase0 + (size_t)64 * KP;
    const int bw0 = (wave * 16) * 32;              // short offset of wave's slab
    const int bw1 = (64 + wave * 16) * 32;

    floatx4 acc[4][4];
#pragma unroll
    for (int i = 0; i < 4; i++)
#pragma unroll
        for (int j = 0; j < 4; j++) acc[i][j] = (floatx4)0.0f;

    float4 ra0, ra1, ra2, ra3;

    // ---- prologue: fill buffer 0 with k-tile 0 (cols < 2000 always valid) ----
    ra0 = *(const float4*)(abase);
    ra1 = *(const float4*)(abase + 4);
    ra2 = *(const float4*)(abase + 8);
    ra3 = *(const float4*)(abase + 12);
    gload16(bbase0, Bs + bw0);
    gload16(bbase1, Bs + bw1);
    {
        unsigned w0 = pkbf(ra0.x, ra0.y), w1 = pkbf(ra0.z, ra0.w);
        unsigned w2 = pkbf(ra1.x, ra1.y), w3 = pkbf(ra1.z, ra1.w);
        unsigned w4 = pkbf(ra2.x, ra2.y), w5 = pkbf(ra2.z, ra2.w);
        unsigned w6 = pkbf(ra3.x, ra3.y), w7 = pkbf(ra3.z, ra3.w);
        *(uint4*)((char*)As + aoff)      = make_uint4(w0, w1, w2, w3);
        *(uint4*)((char*)As + aoff + 16) = make_uint4(w4, w5, w6, w7);
    }
    __syncthreads();

    int p = 0;
    for (int kk = 0; kk < 63; ++kk) {
        unsigned short* an = As + ((p ^ 1) << 12);        // next buffers
        unsigned short* bn = Bs + ((p ^ 1) << 12);
        const unsigned short* ap_ = As + (p << 12);       // current buffers
        const unsigned short* bp_ = Bs + (p << 12);

        const bool pre = (kk < 62);
        if (pre) {
            // issue next k-tile loads early; latency hides under MFMA below
            const float* gp = abase + (size_t)(kk + 1) * 32;
            if ((kk + 1) * 32 + ahalf * 16 < CTX) {       // only kk=61/half=1 pads
                ra0 = *(const float4*)(gp);
                ra1 = *(const float4*)(gp + 4);
                ra2 = *(const float4*)(gp + 8);
                ra3 = *(const float4*)(gp + 12);
            } else {
                ra0 = ra1 = ra2 = ra3 = make_float4(0.f, 0.f, 0.f, 0.f);
            }
            gload16(bbase0 + (kk + 1) * 32, bn + bw0);
            gload16(bbase1 + (kk + 1) * 32, bn + bw1);
        }

        short8 af[4], bfr[4];
#pragma unroll
        for (int i = 0; i < 4; i++)
            af[i] = *(const short8*)&ap_[(wm * 64 + i * 16 + ln) * 32 + quad * 8];
#pragma unroll
        for (int j = 0; j < 4; j++)
            bfr[j] = *(const short8*)&bp_[(wh * 64 + j * 16 + ln) * 32 + quad * 8];
#pragma unroll
        for (int i = 0; i < 4; i++)
#pragma unroll
            for (int j = 0; j < 4; j++)
                acc[i][j] = __builtin_amdgcn_mfma_f32_16x16x32_bf16(af[i], bfr[j], acc[i][j], 0, 0, 0);

        if (pre) {
            // convert prefetched fp32 -> bf16, write into next A buffer
            unsigned w0 = pkbf(ra0.x, ra0.y), w1 = pkbf(ra0.z, ra0.w);
            unsigned w2 = pkbf(ra1.x, ra1.y), w3 = pkbf(ra1.z, ra1.w);
            unsigned w4 = pkbf(ra2.x, ra2.y), w5 = pkbf(ra2.z, ra2.w);
            unsigned w6 = pkbf(ra3.x, ra3.y), w7 = pkbf(ra3.z, ra3.w);
            *(uint4*)((char*)an + aoff)      = make_uint4(w0, w1, w2, w3);
            *(uint4*)((char*)an + aoff + 16) = make_uint4(w4, w5, w6, w7);
        }
        __syncthreads();   // drains vmcnt(0) (B dma) + lgkmcnt(0) (A ds_writes)
        p ^= 1;
    }

    // epilogue: rowsum = sum_h v_a[h] * tanh(acc + W_s[b,h]) for this h-tile
    float rowsum[4][4];
#pragma unroll
    for (int i = 0; i < 4; i++)
#pragma unroll
        for (int r = 0; r < 4; r++) rowsum[i][r] = 0.0f;

#pragma unroll
    for (int j = 0; j < 4; j++) {
        const int h = ht * 128 + wh * 64 + j * 16 + ln;
        float wsv = 0.0f, vav = 0.0f;
        if (h < HID) { wsv = W_s[bb * WSTR + h]; vav = v_a[h]; }
#pragma unroll
        for (int i = 0; i < 4; i++)
#pragma unroll
            for (int r = 0; r < 4; r++)
                rowsum[i][r] += vav * tanhf(acc[i][j][r] + wsv);
    }

    // reduce over 16 h-lanes; wh=0/1 waves and 8 h-blocks combine via atomicAdd
#pragma unroll
    for (int i = 0; i < 4; i++)
#pragma unroll
        for (int r = 0; r < 4; r++) {
            float v = rowsum[i][r];
            v += __shfl_xor(v, 1);
            v += __shfl_xor(v, 2);
            v += __shfl_xor(v, 4);
            v += __shfl_xor(v, 8);
            rowsum[i][r] = v;
        }

    if (ln == 0) {
#pragma unroll
        for (int i = 0; i < 4; i++) {
            const int row = m0 + wm * 64 + i * 16 + quad * 4;
#pragma unroll
            for (int r = 0; r < 4; r++)
                atomicAdd(&out[row + r], rowsum[i][r]);
        }
    }
}

extern "C" void kernel_launch(void* const* d_in, const int* in_sizes, int n_in,
                              void* d_out, int out_size, void* d_ws, size_t ws_size,
                              hipStream_t stream) {
    const float* s_prev = (const float*)d_in[0];
    const float* h_j    = (const float*)d_in[1];
    const float* W_a    = (const float*)d_in[2];
    const float* U_a    = (const float*)d_in[3];
    const float* v_a    = (const float*)d_in[4];
    float* out = (float*)d_out;

    // ws layout: [W_s 64*1024 f32][B_bf HP*KP bf16]   (A_bf pass eliminated)
    const size_t b_off = 64 * WSTR * sizeof(float);
    float* W_s = (float*)d_ws;
    unsigned short* B_bf = (unsigned short*)((char*)d_ws + b_off);

    zero_kernel<<<dim3(M_TOT / 256), 256, 0, stream>>>(out, M_TOT);
    ws_kernel<<<dim3(BATCH * HID / 4), 256, 0, stream>>>(s_prev, W_a, W_s);
    convertB_kernel<<<dim3(HP), 256, 0, stream>>>(U_a, B_bf);
    gemm_kernel<<<dim3((M_TOT / 128) * (HP / 128)), 256, 0, stream>>>(h_j, B_bf, W_s, v_a, out);
}

// Round 2
// 1130.626 us; speedup vs baseline: 1.0691x; 1.0691x over previous
//
#include <hip/hip_runtime.h>
#include <hip/hip_bf16.h>

#define HID 1000
#define CTX 2000
#define KP   2016          // K padded to 63*32
#define HP   1024          // H padded to 8*128
#define BATCH 64
#define NSEQ 1024
#define M_TOT (BATCH * NSEQ)   // 65536
#define WSTR 1024              // W_s row stride

typedef __attribute__((ext_vector_type(8))) short short8;
typedef __attribute__((ext_vector_type(4))) float floatx4;

// fp32 -> bf16 round-to-nearest-even
__device__ __forceinline__ unsigned short f2bf(float x) {
    union { float f; unsigned u; } v; v.f = x;
    unsigned r = v.u + 0x7FFFu + ((v.u >> 16) & 1u);
    return (unsigned short)(r >> 16);
}

// async global->LDS, 16B per lane; LDS dest = wave-uniform base + lane*16
typedef const __attribute__((address_space(1))) unsigned glb_u32;
typedef __attribute__((address_space(3))) unsigned lds_u32;
__device__ __forceinline__ void gload16(const void* g, void* l) {
    __builtin_amdgcn_global_load_lds((glb_u32*)g, (lds_u32*)l, 16, 0, 0);
}

// tanh via exp2-based fast exp; clamp keeps (e-1)/(e+1) finite
__device__ __forceinline__ float fast_tanh(float x) {
    float cx = fminf(fmaxf(x, -15.f), 15.f);
    float e = __expf(2.f * cx);
    return __fdividef(e - 1.f, e + 1.f);
}

__global__ void zero_kernel(float* __restrict__ out, int n) {
    int i = blockIdx.x * 256 + threadIdx.x;
    if (i < n) out[i] = 0.0f;
}

// h_j (M_TOT x CTX fp32) -> A_bf (M_TOT x KP bf16), zero-pad cols >= CTX.
// 16B chunks within each 64B group are stored PRE-SWIZZLED: stored[pc] =
// logical[pc ^ ((row>>1)&3)], so gemm's linear global_load_lds lands the
// swizzled layout in LDS and swizzled ds_reads are bank-conflict-free.
__global__ void convertA_kernel(const float* __restrict__ src, unsigned short* __restrict__ dst) {
    int row = blockIdx.x;
    int t = threadIdx.x;           // one 8-col (16B) chunk per thread
    if (t >= KP / 8) return;       // 252 chunks
    int pc = t & 3, grp = t >> 2;
    int sc = (grp << 2) | (pc ^ ((row >> 1) & 3));   // source logical chunk
    unsigned short pk[8];
    if (sc < CTX / 8) {
        const float* p = src + (size_t)row * CTX + sc * 8;
        float4 a = *(const float4*)p;
        float4 b = *(const float4*)(p + 4);
        pk[0]=f2bf(a.x); pk[1]=f2bf(a.y); pk[2]=f2bf(a.z); pk[3]=f2bf(a.w);
        pk[4]=f2bf(b.x); pk[5]=f2bf(b.y); pk[6]=f2bf(b.z); pk[7]=f2bf(b.w);
    } else {
#pragma unroll
        for (int i = 0; i < 8; i++) pk[i] = 0;
    }
    *(short8*)(dst + (size_t)row * KP + t * 8) = *(short8*)pk;
}

// U_a (HID x CTX fp32) -> B_bf (HP x KP bf16), zero-pad rows >= HID, cols >= CTX.
// Same chunk pre-swizzle as convertA.
__global__ void convertB_kernel(const float* __restrict__ src, unsigned short* __restrict__ dst) {
    int row = blockIdx.x;          // 0..HP-1
    int t = threadIdx.x;
    if (t >= KP / 8) return;
    int pc = t & 3, grp = t >> 2;
    int sc = (grp << 2) | (pc ^ ((row >> 1) & 3));
    unsigned short pk[8];
    if (row < HID && sc < CTX / 8) {
        const float* p = src + (size_t)row * CTX + sc * 8;
        float4 a = *(const float4*)p;
        float4 b = *(const float4*)(p + 4);
        pk[0]=f2bf(a.x); pk[1]=f2bf(a.y); pk[2]=f2bf(a.z); pk[3]=f2bf(a.w);
        pk[4]=f2bf(b.x); pk[5]=f2bf(b.y); pk[6]=f2bf(b.z); pk[7]=f2bf(b.w);
    } else {
#pragma unroll
        for (int i = 0; i < 8; i++) pk[i] = 0;
    }
    *(short8*)(dst + (size_t)row * KP + t * 8) = *(short8*)pk;
}

// W_s[b,h] = sum_d s_prev[b,d] * W_a[h,d] — one wave per (b,h), coalesced row reads
__global__ void ws_kernel(const float* __restrict__ s_prev,
                          const float* __restrict__ W_a,
                          float* __restrict__ W_s) {
    int wave = threadIdx.x >> 6, lane = threadIdx.x & 63;
    int gw = blockIdx.x * 4 + wave;      // 0 .. 63999
    int b = gw / HID, h = gw % HID;
    const float* wr = W_a + (size_t)h * HID;
    const float* sr = s_prev + (size_t)b * HID;
    float acc = 0.0f;
#pragma unroll
    for (int it = 0; it < 4; ++it) {
        int idx = it * 64 + lane;        // float4 index, HID/4 = 250
        if (idx < HID / 4) {
            float4 w = *(const float4*)(wr + idx * 4);
            float4 s = *(const float4*)(sr + idx * 4);
            acc += w.x * s.x + w.y * s.y + w.z * s.z + w.w * s.w;
        }
    }
    acc += __shfl_xor(acc, 1);
    acc += __shfl_xor(acc, 2);
    acc += __shfl_xor(acc, 4);
    acc += __shfl_xor(acc, 8);
    acc += __shfl_xor(acc, 16);
    acc += __shfl_xor(acc, 32);
    if (lane == 0) W_s[b * WSTR + h] = acc;
}

// GEMM: grid = 512 m-panels x 8 h-tiles, XCD-chunked (bid&7 = XCD; the 8
// h-blocks of one m-panel run lockstep on one XCD -> A k-slice shared in L2).
// Double-buffered LDS, one barrier/iter: stage(k+1) -> ds_read+MFMA(k) -> sync.
// LDS layout is chunk-swizzled (baked into A_bf/B_bf storage) so both the
// linear gload16 writes and the swizzled ds_read_b128 are conflict-free.
__global__ __launch_bounds__(256, 4) void gemm_kernel(
        const unsigned short* __restrict__ A, const unsigned short* __restrict__ B,
        const float* __restrict__ W_s, const float* __restrict__ v_a,
        float* __restrict__ out) {
    __shared__ __align__(16) unsigned short As[2 * 128 * 32];  // 2 x 8 KB
    __shared__ __align__(16) unsigned short Bs[2 * 128 * 32];  // 2 x 8 KB

    const int tid  = threadIdx.x;
    const int lane = tid & 63;
    const int wave = tid >> 6;
    const int wm = wave & 1, wh = wave >> 1;
    const int ln = lane & 15, quad = lane >> 4;

    // bijective XCD swizzle: grid 4096 = 8 XCDs x 64 m-panels x 8 h-tiles
    const int bid = blockIdx.x;
    const int xcd = bid & 7, seq = bid >> 3;
    const int m0 = (xcd * 64 + (seq >> 3)) * 128;
    const int ht = seq & 7;
    const int bb = m0 >> 10;           // batch idx (tile never crosses batch)

    // staging: wave w, instr q stages rows [q*64 + w*16, +16); lane -> (l>>2, chunk l&3)
    const int srow = lane >> 2, scol = (lane & 3) * 8;
    const unsigned short* abase0 = A + (size_t)(m0 + wave * 16 + srow) * KP + scol;
    const unsigned short* abase1 = abase0 + (size_t)64 * KP;
    const unsigned short* bbase0 = B + (size_t)(ht * 128 + wave * 16 + srow) * KP + scol;
    const unsigned short* bbase1 = bbase0 + (size_t)64 * KP;
    const int sl0 = (wave * 16) * 32;          // short offset of wave's slab
    const int sl1 = (64 + wave * 16) * 32;

    // fragment-read swizzle: row = ...+ln -> chunk ^= (ln>>1)&3 (in shorts: *8)
    const int rsw = ((ln >> 1) & 3) * 8;

    floatx4 acc[4][4];
#pragma unroll
    for (int i = 0; i < 4; i++)
#pragma unroll
        for (int j = 0; j < 4; j++) acc[i][j] = (floatx4)0.0f;

    // prologue: stage k-tile 0 into buffer 0
    gload16(abase0, As + sl0);
    gload16(abase1, As + sl1);
    gload16(bbase0, Bs + sl0);
    gload16(bbase1, Bs + sl1);
    __syncthreads();

    int p = 0;
    for (int kk = 0; kk < 63; ++kk) {
        if (kk < 62) {   // issue next-tile DMA; latency hides under MFMA below
            const int g = (kk + 1) * 32;
            const int d = ((p ^ 1) << 12);
            gload16(abase0 + g, As + d + sl0);
            gload16(abase1 + g, As + d + sl1);
            gload16(bbase0 + g, Bs + d + sl0);
            gload16(bbase1 + g, Bs + d + sl1);
        }

        const unsigned short* ap_ = As + (p << 12);
        const unsigned short* bp_ = Bs + (p << 12);
        short8 af[4], bfr[4];
#pragma unroll
        for (int i = 0; i < 4; i++)
            af[i] = *(const short8*)&ap_[(wm * 64 + i * 16 + ln) * 32 + (quad * 8 ^ rsw)];
#pragma unroll
        for (int j = 0; j < 4; j++)
            bfr[j] = *(const short8*)&bp_[(wh * 64 + j * 16 + ln) * 32 + (quad * 8 ^ rsw)];
#pragma unroll
        for (int i = 0; i < 4; i++)
#pragma unroll
            for (int j = 0; j < 4; j++)
                acc[i][j] = __builtin_amdgcn_mfma_f32_16x16x32_bf16(af[i], bfr[j], acc[i][j], 0, 0, 0);

        __syncthreads();   // drains DMA (vmcnt) + this iter's ds_reads (lgkm)
        p ^= 1;
    }

    // epilogue: rowsum = sum_h v_a[h] * tanh(acc + W_s[b,h]) for this h-tile
    float rowsum[4][4];
#pragma unroll
    for (int i = 0; i < 4; i++)
#pragma unroll
        for (int r = 0; r < 4; r++) rowsum[i][r] = 0.0f;

#pragma unroll
    for (int j = 0; j < 4; j++) {
        const int h = ht * 128 + wh * 64 + j * 16 + ln;
        float wsv = 0.0f, vav = 0.0f;
        if (h < HID) { wsv = W_s[bb * WSTR + h]; vav = v_a[h]; }
#pragma unroll
        for (int i = 0; i < 4; i++)
#pragma unroll
            for (int r = 0; r < 4; r++)
                rowsum[i][r] += vav * fast_tanh(acc[i][j][r] + wsv);
    }

    // reduce over 16 h-lanes; wh=0/1 waves and 8 h-blocks combine via atomicAdd
#pragma unroll
    for (int i = 0; i < 4; i++)
#pragma unroll
        for (int r = 0; r < 4; r++) {
            float v = rowsum[i][r];
            v += __shfl_xor(v, 1);
            v += __shfl_xor(v, 2);
            v += __shfl_xor(v, 4);
            v += __shfl_xor(v, 8);
            rowsum[i][r] = v;
        }

    if (ln == 0) {
#pragma unroll
        for (int i = 0; i < 4; i++) {
            const int row = m0 + wm * 64 + i * 16 + quad * 4;
#pragma unroll
            for (int r = 0; r < 4; r++)
                atomicAdd(&out[row + r], rowsum[i][r]);
        }
    }
}

extern "C" void kernel_launch(void* const* d_in, const int* in_sizes, int n_in,
                              void* d_out, int out_size, void* d_ws, size_t ws_size,
                              hipStream_t stream) {
    const float* s_prev = (const float*)d_in[0];
    const float* h_j    = (const float*)d_in[1];
    const float* W_a    = (const float*)d_in[2];
    const float* U_a    = (const float*)d_in[3];
    const float* v_a    = (const float*)d_in[4];
    float* out = (float*)d_out;

    // ws layout: [W_s 64*1024 f32][B_bf HP*KP bf16][A_bf M_TOT*KP bf16]
    const size_t b_off = 64 * WSTR * sizeof(float);                 // 262144
    const size_t a_off = b_off + (size_t)HP * KP * sizeof(short);   // +4128768
    float* W_s = (float*)d_ws;
    unsigned short* B_bf = (unsigned short*)((char*)d_ws + b_off);
    unsigned short* A_bf = (unsigned short*)((char*)d_ws + a_off);

    zero_kernel<<<dim3(M_TOT / 256), 256, 0, stream>>>(out, M_TOT);
    ws_kernel<<<dim3(BATCH * HID / 4), 256, 0, stream>>>(s_prev, W_a, W_s);
    convertA_kernel<<<dim3(M_TOT), 256, 0, stream>>>(h_j, A_bf);
    convertB_kernel<<<dim3(HP), 256, 0, stream>>>(U_a, B_bf);
    gemm_kernel<<<dim3((M_TOT / 128) * (HP / 128)), 256, 0, stream>>>(A_bf, B_bf, W_s, v_a, out);
}